// Round 10
// baseline (109.263 us; speedup 1.0000x reference)
//
#include <hip/hip_runtime.h>

#define N 64
#define NC 128
#define NB 8
#define LSEQ 4096
#define QC 128
#define NCHUNK 32

// fp32 regions (float offsets into ws)
#define OFF_ABAR 0
#define OFF_AQ   4096
#define OFF_BBAR 8192          // [n][c] 64x128
#define OFF_ABT  16384
#define OFF_A4   20480
#define OFF_A4T  24576
#define OFF_FS   36864         // [j][b][c][n] 32x8x128x64 fp32
#define U16_BASE (OFF_FS + NCHUNK*NB*NC*N)

// u16 offsets (in u16 units) relative to u16b = (unsigned short*)(ws + U16_BASE)
#define OFF_WH 0                       // [c][n][kq] 128x64x128, kq = 127-p
#define OFF_WL (OFF_WH + NC*N*QC)
#define OFF_UH (OFF_WL + NC*N*QC)      // [c][q][n]
#define OFF_UL (OFF_UH + NC*QC*N)
#define OFF_TH (OFF_UL + NC*QC*N)      // [c][q][kk] Toeplitz k[q-kk]
#define OFF_TL (OFF_TH + NC*QC*QC)
#define OFF_SH (OFF_TL + NC*QC*QC)     // [slot][b][c][n], slot j = S_j (slot0=0)
#define OFF_SL (OFF_SH + NCHUNK*NB*NC*N)

typedef __attribute__((ext_vector_type(8)))  __bf16 bf16x8;
typedef __attribute__((ext_vector_type(16))) float  f32x16;
typedef __attribute__((ext_vector_type(4)))  unsigned int u32x4;

__device__ __forceinline__ float rdlane(float v, int l) {
    return __int_as_float(__builtin_amdgcn_readlane(__float_as_int(v), l));
}

__device__ __forceinline__ void load_row64(const float* __restrict__ p, float (&ar)[64]) {
    const float4* rp = reinterpret_cast<const float4*>(p);
#pragma unroll
    for (int t = 0; t < 16; ++t) {
        float4 v = rp[t];
        ar[4*t+0] = v.x; ar[4*t+1] = v.y; ar[4*t+2] = v.z; ar[4*t+3] = v.w;
    }
}

__device__ __forceinline__ float matvec64(const float (&ar)[64], float v) {
    float a0 = 0.f, a1 = 0.f, a2 = 0.f, a3 = 0.f;
#pragma unroll
    for (int m = 0; m < 64; m += 4) {
        a0 += ar[m+0] * rdlane(v, m+0);
        a1 += ar[m+1] * rdlane(v, m+1);
        a2 += ar[m+2] * rdlane(v, m+2);
        a3 += ar[m+3] * rdlane(v, m+3);
    }
    return (a0 + a1) + (a2 + a3);
}

// fp32 -> (hi, lo) bf16 pair, RNE both
__device__ __forceinline__ void f2bf_hl(float x, unsigned short& hi, unsigned short& lo) {
    unsigned u = __float_as_uint(x);
    unsigned r = (u + 0x7fffu + ((u >> 16) & 1u)) >> 16;
    hi = (unsigned short)r;
    float fh = __uint_as_float(r << 16);
    float l  = x - fh;
    unsigned ul = __float_as_uint(l);
    unsigned rl = (ul + 0x7fffu + ((ul >> 16) & 1u)) >> 16;
    lo = (unsigned short)rl;
}

__device__ __forceinline__ unsigned pack_hl2(float x0, float x1, unsigned& lo32) {
    unsigned short h0, l0, h1, l1;
    f2bf_hl(x0, h0, l0); f2bf_hl(x1, h1, l1);
    lo32 = (unsigned)l0 | ((unsigned)l1 << 16);
    return (unsigned)h0 | ((unsigned)h1 << 16);
}

__device__ __forceinline__ bf16x8 ld_frag(const unsigned short* p) {
    u32x4 v = *(const u32x4*)p;
    return __builtin_bit_cast(bf16x8, v);
}

// ---------------------------------------------------------------------------
// setup: single block, 1024 threads. A_bar solves; A^2; B_bar; A^4. (verified)
// ---------------------------------------------------------------------------
__global__ __launch_bounds__(1024) void setup_kernel(const float* __restrict__ A,
    const float* __restrict__ B, const float* __restrict__ dtp, float* __restrict__ ws)
{
    __shared__ float AT[64*65];    // A^T; reused as A2 (row-major) in stage2
    __shared__ float Ab[64*65];
    __shared__ float AbT[64*65];
    __shared__ float A2T[64*65];
    const int tid = threadIdx.x;
    const int wv  = tid >> 6;
    const int l   = tid & 63;
    const float dt = dtp[0];
    const float h  = 0.5f * dt;

    for (int idx = tid; idx < 4096; idx += 1024) {
        int row = idx >> 6, i = idx & 63;
        AT[i*65 + row] = A[idx];
    }
    __syncthreads();
    const float rdv = 1.0f / (1.0f - h * AT[l*65 + l]);

#pragma unroll 1
    for (int rep = 0; rep < 4; ++rep) {
        const int j = wv + rep*16;
        float r = ((l == j) ? 1.0f : 0.0f) + h * AT[j*65 + l];
#pragma unroll
        for (int i = 0; i < 64; ++i) {
            float xi = rdlane(r, i) * rdlane(rdv, i);
            r = fmaf(h * xi, AT[i*65 + l], r);
            r = (l == i) ? xi : r;
        }
        Ab[l*65 + j]  = r;
        AbT[j*65 + l] = r;
    }
    __syncthreads();

    for (int idx = tid; idx < 4096; idx += 1024) {
        int i = idx >> 6, j = idx & 63;
        ws[OFF_ABAR + idx] = Ab[i*65 + j];
        ws[OFF_ABT + idx]  = AbT[i*65 + j];
    }
    float ar[64];
#pragma unroll
    for (int m2 = 0; m2 < 64; ++m2) ar[m2] = Ab[l*65 + m2];

#pragma unroll 1
    for (int rep = 0; rep < 4; ++rep) {
        const int j = wv + rep*16;
        float v = AbT[j*65 + l];
        float y = matvec64(ar, v);
        AT[l*65 + j]  = y;
        A2T[j*65 + l] = y;
    }
#pragma unroll 1
    for (int rep = 0; rep < 8; ++rep) {
        const int c = wv + rep*16;
        float v = B[l*NC + c];
        float y = matvec64(ar, v);
        ws[OFF_BBAR + l*NC + c] = h * (y + v);
    }
    __syncthreads();

    float a2r[64];
#pragma unroll
    for (int m2 = 0; m2 < 64; ++m2) a2r[m2] = AT[l*65 + m2];
#pragma unroll 1
    for (int rep = 0; rep < 4; ++rep) {
        const int j = wv + rep*16;
        float v = A2T[j*65 + l];
        float y = matvec64(a2r, v);
        ws[OFF_A4 + l*64 + j]  = y;
        ws[OFF_A4T + j*64 + l] = y;
    }
}

// ---------------------------------------------------------------------------
// chains: stride-4 chains with A^4 / (A^4)^T. 4 waves per block.
//   blocks 0..127: W chain + k -> WH/WL + Toeplitz TH/TL
//   blocks 128..255: U chain -> UH/UL
//   blocks 256..271: AQ columns (fp32)
// ---------------------------------------------------------------------------
__global__ __launch_bounds__(256, 1) void chains_kernel(const float* __restrict__ C,
    float* __restrict__ ws)
{
    __shared__ float Wlds[128][65];
    __shared__ float karr[128];
    __shared__ float seed[3][64];
    unsigned short* u16b = (unsigned short*)(ws + U16_BASE);
    const int bid = blockIdx.x;
    const int tid = threadIdx.x;
    const int w4  = tid >> 6;
    const int l   = tid & 63;

    if (bid < 128) {                       // ---- W chain + k + T, channel c
        const int c = bid;
        float a4[64];
        load_row64(ws + OFF_A4 + l*64, a4);
        const float Cl = C[l*NC + c];
        float cur;
        if (w4 == 0) {
            float ab[64];
            load_row64(ws + OFF_ABAR + l*64, ab);
            float t = ws[OFF_BBAR + l*NC + c];
            cur = t;
            t = matvec64(ab, t); seed[0][l] = t;
            t = matvec64(ab, t); seed[1][l] = t;
            t = matvec64(ab, t); seed[2][l] = t;
        }
        __syncthreads();
        if (w4 > 0) cur = seed[w4 - 1][l];
        int p = w4;
#pragma unroll 1
        for (int it = 0; it < 32; ++it) {
            Wlds[p][l] = cur;
            float d = Cl * cur;
            d += __shfl_xor(d, 32, 64); d += __shfl_xor(d, 16, 64);
            d += __shfl_xor(d, 8, 64);  d += __shfl_xor(d, 4, 64);
            d += __shfl_xor(d, 2, 64);  d += __shfl_xor(d, 1, 64);
            if (l == 0) karr[p] = d;
            if (it < 31) { cur = matvec64(a4, cur); p += 4; }
        }
        __syncthreads();
        // WH/WL[c][n][kq], kq = 127-p
        for (int idx = tid; idx < 64*64; idx += 256) {
            int n = idx >> 6, i2 = idx & 63;
            int kq = i2*2;
            float w0 = Wlds[127 - kq][n];
            float w1 = Wlds[126 - kq][n];
            unsigned lo32, hi32 = pack_hl2(w0, w1, lo32);
            ((unsigned*)(u16b + OFF_WH + (c*64 + n)*128))[i2] = hi32;
            ((unsigned*)(u16b + OFF_WL + (c*64 + n)*128))[i2] = lo32;
        }
        // TH/TL[c][q][kk] = k[q-kk] (kk<=q) else 0
        for (int idx = tid; idx < 128*64; idx += 256) {
            int q = idx >> 6, i2 = idx & 63;
            int kk = i2*2;
            float t0 = (kk     <= q) ? karr[q - kk]     : 0.0f;
            float t1 = (kk + 1 <= q) ? karr[q - kk - 1] : 0.0f;
            unsigned lo32, hi32 = pack_hl2(t0, t1, lo32);
            ((unsigned*)(u16b + OFF_TH + (c*QC + q)*QC))[i2] = hi32;
            ((unsigned*)(u16b + OFF_TL + (c*QC + q)*QC))[i2] = lo32;
        }
    } else if (bid < 256) {                // ---- U chain, channel c
        const int c = bid - 128;
        float a4t[64];
        load_row64(ws + OFF_A4T + l*64, a4t);
        float cur;
        if (w4 == 0) {
            float abt[64];
            load_row64(ws + OFF_ABT + l*64, abt);
            float t = C[l*NC + c];
            t = matvec64(abt, t); cur = t;
            t = matvec64(abt, t); seed[0][l] = t;
            t = matvec64(abt, t); seed[1][l] = t;
            t = matvec64(abt, t); seed[2][l] = t;
        }
        __syncthreads();
        if (w4 > 0) cur = seed[w4 - 1][l];
        int q = w4;
#pragma unroll 1
        for (int it = 0; it < 32; ++it) {
            unsigned short hi, lo; f2bf_hl(cur, hi, lo);
            u16b[OFF_UH + (c*QC + q)*64 + l] = hi;
            u16b[OFF_UL + (c*QC + q)*64 + l] = lo;
            if (it < 31) { cur = matvec64(a4t, cur); q += 4; }
        }
    } else {                               // ---- AQ columns (fp32)
        const int j = (bid - 256)*4 + w4;
        float a4[64];
        load_row64(ws + OFF_A4 + l*64, a4);
        float cur = (l == j) ? 1.0f : 0.0f;
#pragma unroll 1
        for (int it = 0; it < 32; ++it) cur = matvec64(a4, cur);
        ws[OFF_AQ + l*64 + j] = cur;
    }
}

// ---------------------------------------------------------------------------
// fchunk (MFMA): per (c, g): F[64 n][64 col] = Wrev @ X, 3-pass bf16 split.
// A-frags direct from global WH/WL; X staged in LDS. (verified R5, 83 µs run)
// ---------------------------------------------------------------------------
__global__ __launch_bounds__(256, 2) void fchunk_mfma_kernel(const float* __restrict__ x,
    float* __restrict__ ws)
{
    __shared__ __align__(16) unsigned Xh32[64*68], Xl32[64*68];   // row stride 136 u16
    const unsigned short* u16b = (const unsigned short*)(ws + U16_BASE);
    const int tid = threadIdx.x;
    const int c = blockIdx.x;
    const int g = blockIdx.y;

    for (int idx = tid; idx < 64*64; idx += 256) {
        int col = idx >> 6, i2 = idx & 63;
        int j = g*8 + (col >> 3), b = col & 7;
        const float2 xv = *reinterpret_cast<const float2*>(
            x + ((long)(b*NC + c))*LSEQ + j*QC + i2*2);
        unsigned lo32, hi32 = pack_hl2(xv.x, xv.y, lo32);
        Xh32[col*68 + i2] = hi32;
        Xl32[col*68 + i2] = lo32;
    }
    __syncthreads();

    const int l = tid & 63;
    const int w = tid >> 6;
    const int lane2 = l & 31;
    const int h = l >> 5;
    const int mt = w & 1;
    const int nt = w >> 1;

    const unsigned short* Xh = (const unsigned short*)Xh32;
    const unsigned short* Xl = (const unsigned short*)Xl32;
    const unsigned short* WHp = u16b + OFF_WH + (c*64 + mt*32 + lane2)*128 + 8*h;
    const unsigned short* WLp = u16b + OFF_WL + (c*64 + mt*32 + lane2)*128 + 8*h;

    f32x16 a0 = {}, a1 = {}, a2 = {};
#pragma unroll
    for (int t = 0; t < 8; ++t) {
        bf16x8 ah = ld_frag(WHp + 16*t);
        bf16x8 al = ld_frag(WLp + 16*t);
        bf16x8 bh = ld_frag(&Xh[(nt*32 + lane2)*136 + 16*t + 8*h]);
        bf16x8 bl = ld_frag(&Xl[(nt*32 + lane2)*136 + 16*t + 8*h]);
        a0 = __builtin_amdgcn_mfma_f32_32x32x16_bf16(ah, bh, a0, 0, 0, 0);
        a1 = __builtin_amdgcn_mfma_f32_32x32x16_bf16(al, bh, a1, 0, 0, 0);
        a2 = __builtin_amdgcn_mfma_f32_32x32x16_bf16(ah, bl, a2, 0, 0, 0);
    }
    f32x16 s = a0 + a1 + a2;
    const int col = g*64 + nt*32 + lane2;
    const int j = col >> 3, b = col & 7;
#pragma unroll
    for (int r = 0; r < 16; ++r) {
        int n = mt*32 + (r & 3) + 8*(r >> 2) + 4*h;
        ws[OFF_FS + ((j*NB + b)*NC + c)*N + n] = s[r];
    }
}

// ---------------------------------------------------------------------------
// scan: per (b,c): S_{j+1} = AQ S_j + F_j; writes bf16 SH/SL slots. (verified R5)
// ---------------------------------------------------------------------------
__global__ __launch_bounds__(64) void scan_kernel(float* __restrict__ ws)
{
    unsigned short* u16b = (unsigned short*)(ws + U16_BASE);
    const int l = threadIdx.x;
    const int b = blockIdx.x >> 7;
    const int c = blockIdx.x & 127;

    float aq[64];
    load_row64(ws + OFF_AQ + l*64, aq);

    u16b[OFF_SH + ((0*NB + b)*NC + c)*64 + l] = 0;   // S_0 = 0
    u16b[OFF_SL + ((0*NB + b)*NC + c)*64 + l] = 0;

    float s = ws[OFF_FS + ((0*NB + b)*NC + c)*N + l];  // S_1
    {
        unsigned short hi, lo; f2bf_hl(s, hi, lo);
        u16b[OFF_SH + ((1*NB + b)*NC + c)*64 + l] = hi;
        u16b[OFF_SL + ((1*NB + b)*NC + c)*64 + l] = lo;
    }
    for (int j = 1; j <= NCHUNK - 2; ++j) {
        float f = ws[OFF_FS + ((j*NB + b)*NC + c)*N + l];
        float a0 = f, a1 = 0.f, a2 = 0.f, a3 = 0.f;
#pragma unroll
        for (int m = 0; m < 64; m += 4) {
            a0 += aq[m+0] * rdlane(s, m+0);
            a1 += aq[m+1] * rdlane(s, m+1);
            a2 += aq[m+2] * rdlane(s, m+2);
            a3 += aq[m+3] * rdlane(s, m+3);
        }
        s = (a0 + a1) + (a2 + a3);
        unsigned short hi, lo; f2bf_hl(s, hi, lo);
        u16b[OFF_SH + (((j+1)*NB + b)*NC + c)*64 + l] = hi;
        u16b[OFF_SL + (((j+1)*NB + b)*NC + c)*64 + l] = lo;
    }
}

// ---------------------------------------------------------------------------
// output (MFMA): per (c, g): Y[128 q][64 col] = [T|U] @ [X;S], 3-pass bf16.
// A-frags (T and U) and S-frags direct from global; X staged in LDS.
// ---------------------------------------------------------------------------
__global__ __launch_bounds__(256, 2) void output_mfma_kernel(const float* __restrict__ x,
    const float* __restrict__ ws, float* __restrict__ out)
{
    __shared__ __align__(16) unsigned Xh32[64*68], Xl32[64*68];
    const unsigned short* u16b = (const unsigned short*)(ws + U16_BASE);
    const int tid = threadIdx.x;
    const int c = blockIdx.x;
    const int g = blockIdx.y;

    for (int idx = tid; idx < 64*64; idx += 256) {
        int col = idx >> 6, i2 = idx & 63;
        int j = g*8 + (col >> 3), b = col & 7;
        const float2 xv = *reinterpret_cast<const float2*>(
            x + ((long)(b*NC + c))*LSEQ + j*QC + i2*2);
        unsigned lo32, hi32 = pack_hl2(xv.x, xv.y, lo32);
        Xh32[col*68 + i2] = hi32;
        Xl32[col*68 + i2] = lo32;
    }
    __syncthreads();

    const int l = tid & 63;
    const int w = tid >> 6;        // m-tile
    const int lane2 = l & 31;
    const int h = l >> 5;
    const int m = w*32 + lane2;    // output row q

    const unsigned short* Xh = (const unsigned short*)Xh32;
    const unsigned short* Xl = (const unsigned short*)Xl32;
    const unsigned short* THp = u16b + OFF_TH + (c*QC + m)*QC + 8*h;
    const unsigned short* TLp = u16b + OFF_TL + (c*QC + m)*QC + 8*h;

    f32x16 a0[2] = {{}, {}}, a1[2] = {{}, {}}, a2[2] = {{}, {}};

#pragma unroll
    for (int t = 0; t < 12; ++t) {
        bf16x8 ah, al;
        if (t < 8) {
            ah = ld_frag(THp + 16*t);
            al = ld_frag(TLp + 16*t);
        } else {
            const unsigned short* up = u16b + (c*QC + m)*64 + 16*(t-8) + 8*h;
            ah = ld_frag(up + OFF_UH);
            al = ld_frag(up + OFF_UL);
        }
#pragma unroll
        for (int nt = 0; nt < 2; ++nt) {
            bf16x8 bh, bl;
            if (t < 8) {
                bh = ld_frag(&Xh[(nt*32 + lane2)*136 + 16*t + 8*h]);
                bl = ld_frag(&Xl[(nt*32 + lane2)*136 + 16*t + 8*h]);
            } else {
                int col = g*64 + nt*32 + lane2;
                int j = col >> 3, b = col & 7;
                const unsigned short* sp = u16b + ((j*NB + b)*NC + c)*64 + 16*(t-8) + 8*h;
                bh = ld_frag(sp + OFF_SH);
                bl = ld_frag(sp + OFF_SL);
            }
            a0[nt] = __builtin_amdgcn_mfma_f32_32x32x16_bf16(ah, bh, a0[nt], 0, 0, 0);
            a1[nt] = __builtin_amdgcn_mfma_f32_32x32x16_bf16(al, bh, a1[nt], 0, 0, 0);
            a2[nt] = __builtin_amdgcn_mfma_f32_32x32x16_bf16(ah, bl, a2[nt], 0, 0, 0);
        }
    }

#pragma unroll
    for (int nt = 0; nt < 2; ++nt) {
        f32x16 s = a0[nt] + a1[nt] + a2[nt];
        int col = g*64 + nt*32 + lane2;
        int j = col >> 3, b = col & 7;
        float* op = out + ((long)(b*NC + c))*LSEQ + j*QC;
#pragma unroll
        for (int r = 0; r < 16; ++r) {
            int row = w*32 + (r & 3) + 8*(r >> 2) + 4*h;
            op[row] = s[r];
        }
    }
}

extern "C" void kernel_launch(void* const* d_in, const int* in_sizes, int n_in,
                              void* d_out, int out_size, void* d_ws, size_t ws_size,
                              hipStream_t stream)
{
    const float* signal = (const float*)d_in[0];
    const float* B      = (const float*)d_in[1];
    const float* C      = (const float*)d_in[2];
    const float* A      = (const float*)d_in[3];
    const float* dt     = (const float*)d_in[4];
    float* ws  = (float*)d_ws;
    float* out = (float*)d_out;

    hipLaunchKernelGGL(setup_kernel,      dim3(1),     dim3(1024), 0, stream, A, B, dt, ws);
    hipLaunchKernelGGL(chains_kernel,     dim3(272),   dim3(256),  0, stream, C, ws);
    hipLaunchKernelGGL(fchunk_mfma_kernel,dim3(NC, 4), dim3(256),  0, stream, signal, ws);
    hipLaunchKernelGGL(scan_kernel,       dim3(NB*NC), dim3(64),   0, stream, ws);
    hipLaunchKernelGGL(output_mfma_kernel,dim3(NC, 4), dim3(256),  0, stream, signal, ws, out);
}

// Round 11
// 83.190 us; speedup vs baseline: 1.3134x; 1.3134x over previous
//
#include <hip/hip_runtime.h>

#define N 64
#define NC 128
#define NB 8
#define LSEQ 4096
#define QC 128
#define NCHUNK 32

// fp32 regions (float offsets into ws)
#define OFF_ABAR 0
#define OFF_AQ   4096
#define OFF_BBAR 8192          // [n][c] 64x128
#define OFF_ABT  16384
#define OFF_A2   20480
#define OFF_A2T  24576
#define OFF_A4   28672
#define OFF_A4T  32768
#define OFF_FS   36864         // [j][b][c][n] 32x8x128x64 fp32 (F values from fchunk)
#define U16_BASE (OFF_FS + NCHUNK*NB*NC*N)   // u16 planes start here (16B aligned)

// u16 offsets (in u16 units) relative to u16b = (unsigned short*)(ws + U16_BASE)
#define OFF_WH 0                       // [c][n][kq] 128x64x128, kq = 127-p
#define OFF_WL (OFF_WH + NC*N*QC)
#define OFF_UH (OFF_WL + NC*N*QC)      // [c][q][n]
#define OFF_UL (OFF_UH + NC*QC*N)
#define OFF_KH (OFF_UL + NC*QC*N)      // [c][256] reversed-extended k
#define OFF_KL (OFF_KH + NC*256)
#define OFF_SH (OFF_KL + NC*256)       // [slot][b][c][n], slot j holds S_j (slot0 = 0)
#define OFF_SL (OFF_SH + NCHUNK*NB*NC*N)

typedef __attribute__((ext_vector_type(8)))  __bf16 bf16x8;
typedef __attribute__((ext_vector_type(16))) float  f32x16;
typedef __attribute__((ext_vector_type(4)))  unsigned int u32x4;

__device__ __forceinline__ float rdlane(float v, int l) {
    return __int_as_float(__builtin_amdgcn_readlane(__float_as_int(v), l));
}

__device__ __forceinline__ void load_row64(const float* __restrict__ p, float (&ar)[64]) {
    const float4* rp = reinterpret_cast<const float4*>(p);
#pragma unroll
    for (int t = 0; t < 16; ++t) {
        float4 v = rp[t];
        ar[4*t+0] = v.x; ar[4*t+1] = v.y; ar[4*t+2] = v.z; ar[4*t+3] = v.w;
    }
}

__device__ __forceinline__ float matvec64(const float (&ar)[64], float v) {
    float a0 = 0.f, a1 = 0.f, a2 = 0.f, a3 = 0.f;
#pragma unroll
    for (int m = 0; m < 64; m += 4) {
        a0 += ar[m+0] * rdlane(v, m+0);
        a1 += ar[m+1] * rdlane(v, m+1);
        a2 += ar[m+2] * rdlane(v, m+2);
        a3 += ar[m+3] * rdlane(v, m+3);
    }
    return (a0 + a1) + (a2 + a3);
}

// fp32 -> (hi, lo) bf16 pair, RNE both
__device__ __forceinline__ void f2bf_hl(float x, unsigned short& hi, unsigned short& lo) {
    unsigned u = __float_as_uint(x);
    unsigned r = (u + 0x7fffu + ((u >> 16) & 1u)) >> 16;
    hi = (unsigned short)r;
    float fh = __uint_as_float(r << 16);
    float l  = x - fh;
    unsigned ul = __float_as_uint(l);
    unsigned rl = (ul + 0x7fffu + ((ul >> 16) & 1u)) >> 16;
    lo = (unsigned short)rl;
}

// pack two fp32 -> hi-plane u32 (returned) and lo-plane u32 (out-param)
__device__ __forceinline__ unsigned pack_hl2(float x0, float x1, unsigned& lo32) {
    unsigned short h0, l0, h1, l1;
    f2bf_hl(x0, h0, l0); f2bf_hl(x1, h1, l1);
    lo32 = (unsigned)l0 | ((unsigned)l1 << 16);
    return (unsigned)h0 | ((unsigned)h1 << 16);
}

__device__ __forceinline__ bf16x8 ld_frag(const unsigned short* p) {
    u32x4 v = *(const u32x4*)p;     // 16B-aligned by construction
    return __builtin_bit_cast(bf16x8, v);
}

__device__ __forceinline__ bf16x8 pack8(const unsigned short* v) {
    u32x4 u;
    u.x = v[0] | ((unsigned)v[1] << 16);
    u.y = v[2] | ((unsigned)v[3] << 16);
    u.z = v[4] | ((unsigned)v[5] << 16);
    u.w = v[6] | ((unsigned)v[7] << 16);
    return __builtin_bit_cast(bf16x8, u);
}

// ---------------------------------------------------------------------------
// prep_cols: forward-substitution column solves of (I - h A) x = v.
// ---------------------------------------------------------------------------
__global__ __launch_bounds__(256) void prep_cols_kernel(const float* __restrict__ A,
    const float* __restrict__ B, const float* __restrict__ dtp,
    float* __restrict__ ws)
{
    __shared__ float AT[64*65];    // AT[i][l] = A[l][i]
    const int tid  = threadIdx.x;
    const int wave = tid >> 6;
    const int l    = tid & 63;
    const float dt = dtp[0];
    const float h  = 0.5f * dt;

    for (int idx = tid; idx < 64*64; idx += 256) {
        int row = idx >> 6, i = idx & 63;
        AT[i*65 + row] = A[idx];
    }
    __syncthreads();

    const float rdv = 1.0f / (1.0f - h * AT[l*65 + l]);
    const int colid = blockIdx.x * 4 + wave;

    float r;
    if (colid < 64) {
        int j = colid;
        r = ((l == j) ? 1.0f : 0.0f) + h * AT[j*65 + l];
    } else {
        int c = colid - 64;
        r = B[l*NC + c];
    }

#pragma unroll
    for (int i = 0; i < 64; ++i) {
        float xi = rdlane(r, i) * rdlane(rdv, i);
        float a  = AT[i*65 + l];
        r = fmaf(h * xi, a, r);
        r = (l == i) ? xi : r;
    }

    if (colid < 64) {
        ws[OFF_ABAR + l*64 + colid] = r;
        ws[OFF_ABT  + colid*64 + l] = r;
    } else {
        ws[OFF_BBAR + l*NC + (colid - 64)] = dt * r;
    }
}

// ---------------------------------------------------------------------------
// pow_sq: dst = src^2 (and transpose). Column j per wave: one matvec.
// ---------------------------------------------------------------------------
__global__ __launch_bounds__(256) void pow_sq_kernel(const float* __restrict__ src,
    const float* __restrict__ srcT, float* __restrict__ dst, float* __restrict__ dstT)
{
    const int tid = threadIdx.x;
    const int wave = tid >> 6;
    const int l = tid & 63;
    const int j = blockIdx.x * 4 + wave;

    float ar[64];
    load_row64(src + l*64, ar);
    float x = srcT[j*64 + l];
    float y = matvec64(ar, x);
    dst[l*64 + j]  = y;
    dstT[j*64 + l] = y;
}

// ---------------------------------------------------------------------------
// chains: stride-4 chains with A^4 / (A^4)^T. 4 waves per block.
//   blocks   0..127 : W chain for channel c -> WH/WL (bf16, [n][kq] reversed)
//                     + inline k-dot -> KH/KL (reversed-extended, bf16)
//   blocks 128..255 : U chain for channel c -> UH/UL (bf16, [q][n])
//   blocks 256..271 : AQ columns (fp32, for scan)
// ---------------------------------------------------------------------------
__global__ __launch_bounds__(256, 1) void chains_kernel(const float* __restrict__ C,
    float* __restrict__ ws)
{
    __shared__ float Wlds[128][65];
    __shared__ float karr[128];
    __shared__ float seed[3][64];
    unsigned short* u16b = (unsigned short*)(ws + U16_BASE);
    const int bid = blockIdx.x;
    const int tid = threadIdx.x;
    const int w4  = tid >> 6;
    const int l   = tid & 63;

    if (bid < 128) {                       // ---- W chain + k, channel c
        const int c = bid;
        float a4[64];
        load_row64(ws + OFF_A4 + l*64, a4);
        const float Cl = C[l*NC + c];
        float cur;
        if (w4 == 0) {
            float ab[64];
            load_row64(ws + OFF_ABAR + l*64, ab);
            float t = ws[OFF_BBAR + l*NC + c];
            cur = t;
            t = matvec64(ab, t); seed[0][l] = t;
            t = matvec64(ab, t); seed[1][l] = t;
            t = matvec64(ab, t); seed[2][l] = t;
        }
        __syncthreads();
        if (w4 > 0) cur = seed[w4 - 1][l];
        int p = w4;
#pragma unroll 1
        for (int it = 0; it < 32; ++it) {
            Wlds[p][l] = cur;
            float d = Cl * cur;                      // off-critical-path k-dot
            d += __shfl_xor(d, 32, 64); d += __shfl_xor(d, 16, 64);
            d += __shfl_xor(d, 8, 64);  d += __shfl_xor(d, 4, 64);
            d += __shfl_xor(d, 2, 64);  d += __shfl_xor(d, 1, 64);
            if (l == 0) karr[p] = d;
            if (it < 31) { cur = matvec64(a4, cur); p += 4; }
        }
        __syncthreads();
        // WH/WL[c][n][kq], kq = 127-p, packed u32 writes (coalesced)
        for (int idx = tid; idx < 64*64; idx += 256) {
            int n = idx >> 6, i2 = idx & 63;
            int kq = i2*2;
            float w0 = Wlds[127 - kq][n];
            float w1 = Wlds[126 - kq][n];
            unsigned lo32, hi32 = pack_hl2(w0, w1, lo32);
            ((unsigned*)(u16b + OFF_WH + (c*64 + n)*128))[i2] = hi32;
            ((unsigned*)(u16b + OFF_WL + (c*64 + n)*128))[i2] = lo32;
        }
        // KH/KL[c][I]: I<128 -> k[127-I], else 0
        if (tid < 128) {
            int i = tid;                 // u32 index = entries (2i, 2i+1)
            float k0 = (2*i   < 128) ? karr[127 - 2*i] : 0.0f;
            float k1 = (2*i+1 < 128) ? karr[126 - 2*i] : 0.0f;
            unsigned lo32, hi32 = pack_hl2(k0, k1, lo32);
            ((unsigned*)(u16b + OFF_KH + c*256))[i] = hi32;
            ((unsigned*)(u16b + OFF_KL + c*256))[i] = lo32;
        }
    } else if (bid < 256) {                // ---- U chain, channel c
        const int c = bid - 128;
        float a4t[64];
        load_row64(ws + OFF_A4T + l*64, a4t);
        float cur;
        if (w4 == 0) {
            float abt[64];
            load_row64(ws + OFF_ABT + l*64, abt);
            float t = C[l*NC + c];
            t = matvec64(abt, t); cur = t;            // U_0
            t = matvec64(abt, t); seed[0][l] = t;     // U_1
            t = matvec64(abt, t); seed[1][l] = t;     // U_2
            t = matvec64(abt, t); seed[2][l] = t;     // U_3
        }
        __syncthreads();
        if (w4 > 0) cur = seed[w4 - 1][l];
        int q = w4;
#pragma unroll 1
        for (int it = 0; it < 32; ++it) {
            unsigned short hi, lo; f2bf_hl(cur, hi, lo);
            u16b[OFF_UH + (c*QC + q)*64 + l] = hi;
            u16b[OFF_UL + (c*QC + q)*64 + l] = lo;
            if (it < 31) { cur = matvec64(a4t, cur); q += 4; }
        }
    } else {                               // ---- AQ columns (fp32)
        const int j = (bid - 256)*4 + w4;
        float a4[64];
        load_row64(ws + OFF_A4 + l*64, a4);
        float cur = (l == j) ? 1.0f : 0.0f;
#pragma unroll 1
        for (int it = 0; it < 32; ++it) cur = matvec64(a4, cur);
        ws[OFF_AQ + l*64 + j] = cur;
    }
}

// ---------------------------------------------------------------------------
// fchunk (MFMA): per (c, g): F[64 n][64 col] = Wrev @ X, 3-pass bf16 split.
// A-frags direct from global WH/WL; X staged in LDS (vectorized convert).
// ---------------------------------------------------------------------------
__global__ __launch_bounds__(256, 2) void fchunk_mfma_kernel(const float* __restrict__ x,
    float* __restrict__ ws)
{
    __shared__ __align__(16) unsigned Xh32[64*68], Xl32[64*68];   // row stride 136 u16
    const unsigned short* u16b = (const unsigned short*)(ws + U16_BASE);
    const int tid = threadIdx.x;
    const int c = blockIdx.x;
    const int g = blockIdx.y;

    for (int idx = tid; idx < 64*64; idx += 256) {
        int col = idx >> 6, i2 = idx & 63;
        int j = g*8 + (col >> 3), b = col & 7;
        const float2 xv = *reinterpret_cast<const float2*>(
            x + ((long)(b*NC + c))*LSEQ + j*QC + i2*2);
        unsigned lo32, hi32 = pack_hl2(xv.x, xv.y, lo32);
        Xh32[col*68 + i2] = hi32;
        Xl32[col*68 + i2] = lo32;
    }
    __syncthreads();

    const int l = tid & 63;
    const int w = tid >> 6;
    const int lane2 = l & 31;
    const int h = l >> 5;
    const int mt = w & 1;
    const int nt = w >> 1;

    const unsigned short* Xh = (const unsigned short*)Xh32;
    const unsigned short* Xl = (const unsigned short*)Xl32;
    const unsigned short* WHp = u16b + OFF_WH + (c*64 + mt*32 + lane2)*128 + 8*h;
    const unsigned short* WLp = u16b + OFF_WL + (c*64 + mt*32 + lane2)*128 + 8*h;

    f32x16 a0 = {}, a1 = {}, a2 = {};
#pragma unroll
    for (int t = 0; t < 8; ++t) {
        bf16x8 ah = ld_frag(WHp + 16*t);
        bf16x8 al = ld_frag(WLp + 16*t);
        bf16x8 bh = ld_frag(&Xh[(nt*32 + lane2)*136 + 16*t + 8*h]);
        bf16x8 bl = ld_frag(&Xl[(nt*32 + lane2)*136 + 16*t + 8*h]);
        a0 = __builtin_amdgcn_mfma_f32_32x32x16_bf16(ah, bh, a0, 0, 0, 0);
        a1 = __builtin_amdgcn_mfma_f32_32x32x16_bf16(al, bh, a1, 0, 0, 0);
        a2 = __builtin_amdgcn_mfma_f32_32x32x16_bf16(ah, bl, a2, 0, 0, 0);
    }
    f32x16 s = a0 + a1 + a2;
    const int col = g*64 + nt*32 + lane2;
    const int j = col >> 3, b = col & 7;
#pragma unroll
    for (int r = 0; r < 16; ++r) {
        int n = mt*32 + (r & 3) + 8*(r >> 2) + 4*h;
        ws[OFF_FS + ((j*NB + b)*NC + c)*N + n] = s[r];
    }
}

// ---------------------------------------------------------------------------
// scan: per (b,c): S_{j+1} = AQ S_j + F_j; writes bf16 SH/SL slots (slot j = S_j).
// ---------------------------------------------------------------------------
__global__ __launch_bounds__(64) void scan_kernel(float* __restrict__ ws)
{
    unsigned short* u16b = (unsigned short*)(ws + U16_BASE);
    const int l = threadIdx.x;
    const int b = blockIdx.x >> 7;
    const int c = blockIdx.x & 127;

    float aq[64];
    load_row64(ws + OFF_AQ + l*64, aq);

    u16b[OFF_SH + ((0*NB + b)*NC + c)*64 + l] = 0;   // S_0 = 0
    u16b[OFF_SL + ((0*NB + b)*NC + c)*64 + l] = 0;

    float s = ws[OFF_FS + ((0*NB + b)*NC + c)*N + l];  // S_1
    {
        unsigned short hi, lo; f2bf_hl(s, hi, lo);
        u16b[OFF_SH + ((1*NB + b)*NC + c)*64 + l] = hi;
        u16b[OFF_SL + ((1*NB + b)*NC + c)*64 + l] = lo;
    }
    for (int j = 1; j <= NCHUNK - 2; ++j) {
        float f = ws[OFF_FS + ((j*NB + b)*NC + c)*N + l];
        float a0 = f, a1 = 0.f, a2 = 0.f, a3 = 0.f;
#pragma unroll
        for (int m = 0; m < 64; m += 4) {
            a0 += aq[m+0] * rdlane(s, m+0);
            a1 += aq[m+1] * rdlane(s, m+1);
            a2 += aq[m+2] * rdlane(s, m+2);
            a3 += aq[m+3] * rdlane(s, m+3);
        }
        s = (a0 + a1) + (a2 + a3);
        unsigned short hi, lo; f2bf_hl(s, hi, lo);
        u16b[OFF_SH + (((j+1)*NB + b)*NC + c)*64 + l] = hi;
        u16b[OFF_SL + (((j+1)*NB + b)*NC + c)*64 + l] = lo;
    }
}

// ---------------------------------------------------------------------------
// output (MFMA): per (c, g): Y[128 q][64 col] = [T|U] @ [X;S], 3-pass bf16.
// T gathered from LDS kr; U-frags and S-frags direct from global bf16 planes.
// ---------------------------------------------------------------------------
__global__ __launch_bounds__(256, 2) void output_mfma_kernel(const float* __restrict__ x,
    const float* __restrict__ ws, float* __restrict__ out)
{
    __shared__ __align__(16) unsigned krh32[128], krl32[128];
    __shared__ __align__(16) unsigned Xh32[64*68], Xl32[64*68];
    const unsigned short* u16b = (const unsigned short*)(ws + U16_BASE);
    const int tid = threadIdx.x;
    const int c = blockIdx.x;
    const int g = blockIdx.y;

    if (tid < 128) {
        krh32[tid] = ((const unsigned*)(u16b + OFF_KH + c*256))[tid];
        krl32[tid] = ((const unsigned*)(u16b + OFF_KL + c*256))[tid];
    }
    for (int idx = tid; idx < 64*64; idx += 256) {
        int col = idx >> 6, i2 = idx & 63;
        int j = g*8 + (col >> 3), b = col & 7;
        const float2 xv = *reinterpret_cast<const float2*>(
            x + ((long)(b*NC + c))*LSEQ + j*QC + i2*2);
        unsigned lo32, hi32 = pack_hl2(xv.x, xv.y, lo32);
        Xh32[col*68 + i2] = hi32;
        Xl32[col*68 + i2] = lo32;
    }
    __syncthreads();

    const int l = tid & 63;
    const int w = tid >> 6;        // m-tile
    const int lane2 = l & 31;
    const int h = l >> 5;
    const int m = w*32 + lane2;    // output row q

    const unsigned short* krh = (const unsigned short*)krh32;
    const unsigned short* krl = (const unsigned short*)krl32;
    const unsigned short* Xh = (const unsigned short*)Xh32;
    const unsigned short* Xl = (const unsigned short*)Xl32;

    f32x16 a0[2] = {{}, {}}, a1[2] = {{}, {}}, a2[2] = {{}, {}};

#pragma unroll
    for (int t = 0; t < 12; ++t) {
        bf16x8 ah, al;
        if (t < 8) {
            int I0 = 127 - m + 16*t + 8*h;
            unsigned short vh[8], vl[8];
#pragma unroll
            for (int e = 0; e < 8; ++e) { vh[e] = krh[I0 + e]; vl[e] = krl[I0 + e]; }
            ah = pack8(vh); al = pack8(vl);
        } else {
            const unsigned short* up = u16b + (c*QC + m)*64 + 16*(t-8) + 8*h;
            ah = ld_frag(up + OFF_UH);
            al = ld_frag(up + OFF_UL);
        }
#pragma unroll
        for (int nt = 0; nt < 2; ++nt) {
            bf16x8 bh, bl;
            if (t < 8) {
                bh = ld_frag(&Xh[(nt*32 + lane2)*136 + 16*t + 8*h]);
                bl = ld_frag(&Xl[(nt*32 + lane2)*136 + 16*t + 8*h]);
            } else {
                int col = g*64 + nt*32 + lane2;
                int j = col >> 3, b = col & 7;
                const unsigned short* sp = u16b + ((j*NB + b)*NC + c)*64 + 16*(t-8) + 8*h;
                bh = ld_frag(sp + OFF_SH);
                bl = ld_frag(sp + OFF_SL);
            }
            a0[nt] = __builtin_amdgcn_mfma_f32_32x32x16_bf16(ah, bh, a0[nt], 0, 0, 0);
            a1[nt] = __builtin_amdgcn_mfma_f32_32x32x16_bf16(al, bh, a1[nt], 0, 0, 0);
            a2[nt] = __builtin_amdgcn_mfma_f32_32x32x16_bf16(ah, bl, a2[nt], 0, 0, 0);
        }
    }

#pragma unroll
    for (int nt = 0; nt < 2; ++nt) {
        f32x16 s = a0[nt] + a1[nt] + a2[nt];
        int col = g*64 + nt*32 + lane2;
        int j = col >> 3, b = col & 7;
        float* op = out + ((long)(b*NC + c))*LSEQ + j*QC;
#pragma unroll
        for (int r = 0; r < 16; ++r) {
            int row = w*32 + (r & 3) + 8*(r >> 2) + 4*h;
            op[row] = s[r];
        }
    }
}

extern "C" void kernel_launch(void* const* d_in, const int* in_sizes, int n_in,
                              void* d_out, int out_size, void* d_ws, size_t ws_size,
                              hipStream_t stream)
{
    const float* signal = (const float*)d_in[0];
    const float* B      = (const float*)d_in[1];
    const float* C      = (const float*)d_in[2];
    const float* A      = (const float*)d_in[3];
    const float* dt     = (const float*)d_in[4];
    float* ws  = (float*)d_ws;
    float* out = (float*)d_out;

    hipLaunchKernelGGL(prep_cols_kernel,  dim3(48),     dim3(256), 0, stream, A, B, dt, ws);
    hipLaunchKernelGGL(pow_sq_kernel,     dim3(16),     dim3(256), 0, stream,
                       ws + OFF_ABAR, ws + OFF_ABT, ws + OFF_A2, ws + OFF_A2T);
    hipLaunchKernelGGL(pow_sq_kernel,     dim3(16),     dim3(256), 0, stream,
                       ws + OFF_A2, ws + OFF_A2T, ws + OFF_A4, ws + OFF_A4T);
    hipLaunchKernelGGL(chains_kernel,     dim3(272),    dim3(256), 0, stream, C, ws);
    hipLaunchKernelGGL(fchunk_mfma_kernel,dim3(NC, 4),  dim3(256), 0, stream, signal, ws);
    hipLaunchKernelGGL(scan_kernel,       dim3(NB*NC),  dim3(64),  0, stream, ws);
    hipLaunchKernelGGL(output_mfma_kernel,dim3(NC, 4),  dim3(256), 0, stream, signal, ws, out);
}